// Round 7
// baseline (16334.669 us; speedup 1.0000x reference)
//
#include <hip/hip_runtime.h>

// PredictorRNN: 2076 sequential GRU steps in ONE persistent kernel.
// Round-17 = round-16 two-chain structure with the sweep ISSUE POINTS FIXED.
// r16 (12.2ms, correct) proved the two-chain schedule serialized both
// communication waits: sweeps were issued post-barrier inside the OTHER
// chain's half-step (only ~800cy flight) and the second sweep was issued
// only after the first verify completed. Fix: issue each chain's sweep at
// the TOP of the half-step that follows its producer's stores:
//   A-half(s) top: issue vB for h^{s-1}_B (B stored it ~200cy ago)
//   B-half(s) top: issue vA for h^s_A   (A stored it ~200cy ago)
// => every sweep gets a FULL half-step of flight, and both chains'
// communications are in flight simultaneously (overlapping stalls).
// Verify-retry: first recheck reloads immediately (no sleep) — after a
// half-step of flight the data is almost certainly visible; sleep(2) only
// between subsequent rounds. Tagged protocol per chain unchanged (data is
// the signal; retry-until-tagged => timing never affects correctness).
// 64 blocks x 256 threads; each block: 2 independent 16-row slabs
// (A = rows (bx&7)*16, B = rows (bx&7+8)*16), 64 j-columns; weights
// register-resident (216 VGPRs); VGPR_Count 256, no spill (r16-verified).

typedef __attribute__((ext_vector_type(8))) short short8;   // 8 x bf16 frag
typedef __attribute__((ext_vector_type(4))) float floatx4;

#define B_    256
#define T_    256
#define I_    64
#define H_    512
#define HZ    8
#define LPAD  520            // LDS staging pitch (ushorts), rows 16B-aligned
#define HLSZ  (16 * LPAD)    // one staging buffer (16 rows)

#define MFMA_BF16(acc, a, b) \
  acc = __builtin_amdgcn_mfma_f32_16x16x32_bf16((a), (b), (acc), 0, 0, 0)

// escalating backoff for the (rare, 28-step) tagged xext poll — champion tuning
#define POLL_BACKOFF(it)                         \
  do {                                           \
    if ((it) < 2)      __builtin_amdgcn_s_sleep(1);  \
    else if ((it) < 8) __builtin_amdgcn_s_sleep(4);  \
    else               __builtin_amdgcn_s_sleep(16); \
  } while (0)

__device__ __forceinline__ float bf2f(unsigned short u) {
  union { unsigned int i; float f; } v; v.i = ((unsigned int)u) << 16; return v.f;
}
__device__ __forceinline__ unsigned short f2bf(float f) {
  union { float f; unsigned int i; } v; v.f = f;
  return (unsigned short)((v.i + 0x7FFFu + ((v.i >> 16) & 1u)) >> 16);  // RNE
}
__device__ __forceinline__ short8 ld8_f32_to_bf16(const float* p) {
  short8 r;
#pragma unroll
  for (int e = 0; e < 8; ++e) r[e] = (short)f2bf(p[e]);
  return r;
}
__device__ __forceinline__ float sigm(float xx) {
  return __builtin_amdgcn_rcpf(1.f + __expf(-xx));
}
__device__ __forceinline__ float tanh_fast(float xx) {
  float e = __expf(2.f * xx);                 // +inf -> 1, 0 -> -1
  return 1.f - 2.f * __builtin_amdgcn_rcpf(e + 1.f);
}
// relaxed agent-scope atomics (lower to global ops with L1/L2 bypass -> MALL)
__device__ __forceinline__ unsigned long long ald64(const unsigned int* p) {
  return __hip_atomic_load((const unsigned long long*)p, __ATOMIC_RELAXED,
                           __HIP_MEMORY_SCOPE_AGENT);
}
__device__ __forceinline__ void ast32(unsigned int* p, unsigned int v) {
  __hip_atomic_store(p, v, __ATOMIC_RELAXED, __HIP_MEMORY_SCOPE_AGENT);
}

// issue the 16x8B speculative sweep for a slab (rows rowb..rowb+15, parity par)
#define ISSUE_SWEEP(v, rowb, par)                                          \
  do {                                                                     \
    const unsigned int* hbp_ = hbuf + (size_t)(par) * (B_ * H_) +          \
                               (size_t)(rowb) * H_;                        \
    _Pragma("unroll") for (int i_ = 0; i_ < 16; ++i_)                      \
        v[i_] = ald64(hbp_ + (size_t)i_ * H_ + 2 * tid);                   \
  } while (0)

// verify a previously issued sweep (retry stale words; first recheck has no
// sleep — after a half-step of flight the data is almost certainly visible)
// and unpack the bf16 payload into LDS rows
#define VERIFY_STAGE(v, rowb, par, want_, hl)                              \
  do {                                                                     \
    const unsigned int* hbp_ = hbuf + (size_t)(par) * (B_ * H_) +          \
                               (size_t)(rowb) * H_;                        \
    const unsigned int want__ = (unsigned int)(want_);                     \
    int it_ = 0;                                                           \
    for (;;) {                                                             \
      bool all_ = true;                                                    \
      _Pragma("unroll") for (int i_ = 0; i_ < 16; ++i_) {                  \
        unsigned int w0_ = (unsigned int)v[i_];                            \
        unsigned int w1_ = (unsigned int)(v[i_] >> 32);                    \
        if (((w0_ >> 16) != want__) || ((w1_ >> 16) != want__))            \
          all_ = false;                                                    \
      }                                                                    \
      if (all_) break;                                                     \
      if (it_ > 0) __builtin_amdgcn_s_sleep(2);                            \
      _Pragma("unroll") for (int i_ = 0; i_ < 16; ++i_) {                  \
        unsigned int w0_ = (unsigned int)v[i_];                            \
        unsigned int w1_ = (unsigned int)(v[i_] >> 32);                    \
        if (((w0_ >> 16) != want__) || ((w1_ >> 16) != want__))            \
          v[i_] = ald64(hbp_ + (size_t)i_ * H_ + 2 * tid);                 \
      }                                                                    \
      ++it_;                                                               \
    }                                                                      \
    _Pragma("unroll") for (int i_ = 0; i_ < 16; ++i_) {                    \
      unsigned int w0_ = (unsigned int)v[i_];                              \
      unsigned int w1_ = (unsigned int)(v[i_] >> 32);                      \
      *(unsigned int*)&hl[i_ * LPAD + 2 * tid] =                           \
          (w0_ & 0xffffu) | (w1_ << 16);                                   \
    }                                                                      \
  } while (0)

// one half-step of chain C (rows RC, LDS HLC, carry HLOC, sweep VC) at (s,t).
// TOP: issue the OTHER chain's sweep (VO, rows RO, parity IP) — its producer
// stored ~200cy ago; the sweep flies across this ENTIRE half-step.
#define HALF_STEP(RC, HLC, HLOC, VC, RO, VO, IP, DOISSUE)                  \
  do {                                                                     \
    if (DOISSUE) ISSUE_SWEEP(VO, RO, IP);                                  \
    short8 xaf0, xaf1;                                                     \
    if (t < T_) {                                                          \
      const float* xs_ =                                                   \
          x + ((size_t)((RC) + n16) * T_ + t) * I_ + quad * 8;             \
      xaf0 = ld8_f32_to_bf16(xs_);                                         \
      xaf1 = ld8_f32_to_bf16(xs_ + 32);                                    \
    }                                                                      \
    unsigned short* hl = (HLC) + (s & 1) * HLSZ;                           \
    if (s > 0) {                                                           \
      VERIFY_STAGE(VC, RC, (s + 1) & 1, s, hl);                            \
    } else {                                                               \
      _Pragma("unroll") for (int i_ = 0; i_ < 16; ++i_)                    \
          *(unsigned int*)&hl[i_ * LPAD + 2 * tid] = 0u;                   \
    }                                                                      \
    if (t >= T_) {                                                         \
      const int p2_ = t - T_;                                              \
      const unsigned int wx_ = (unsigned int)(p2_ + 1);                    \
      const unsigned int* xb_ =                                            \
          xext + ((size_t)p2_ * B_ + (RC) + n16) * I_;                     \
      unsigned long long u_[8];                                            \
      _Pragma("unroll") for (int k_ = 0; k_ < 8; ++k_) {                   \
        int off_ = (k_ < 4) ? (quad * 8 + 2 * k_)                          \
                            : (32 + quad * 8 + 2 * (k_ - 4));              \
        u_[k_] = ald64(xb_ + off_);                                        \
      }                                                                    \
      int it_ = 0;                                                         \
      for (;;) {                                                           \
        bool all_ = true;                                                  \
        _Pragma("unroll") for (int k_ = 0; k_ < 8; ++k_) {                 \
          unsigned int w0_ = (unsigned int)u_[k_];                         \
          unsigned int w1_ = (unsigned int)(u_[k_] >> 32);                 \
          if (((w0_ >> 16) != wx_) || ((w1_ >> 16) != wx_)) {              \
            all_ = false;                                                  \
            int off_ = (k_ < 4) ? (quad * 8 + 2 * k_)                      \
                                : (32 + quad * 8 + 2 * (k_ - 4));          \
            u_[k_] = ald64(xb_ + off_);                                    \
          }                                                                \
        }                                                                  \
        if (all_) break;                                                   \
        POLL_BACKOFF(it_);                                                 \
        ++it_;                                                             \
      }                                                                    \
      _Pragma("unroll") for (int k_ = 0; k_ < 4; ++k_) {                   \
        xaf0[2 * k_]     = (short)(unsigned short)u_[k_];                  \
        xaf0[2 * k_ + 1] = (short)(unsigned short)(u_[k_] >> 32);          \
        xaf1[2 * k_]     = (short)(unsigned short)u_[4 + k_];              \
        xaf1[2 * k_ + 1] = (short)(unsigned short)(u_[4 + k_] >> 32);      \
      }                                                                    \
    }                                                                      \
    __syncthreads();                                                       \
    short8 haf[16];                                                        \
    _Pragma("unroll") for (int kc = 0; kc < 16; ++kc)                      \
        haf[kc] = *(const short8*)&hl[n16 * LPAD + kc * 32 + quad * 8];    \
    floatx4 aR = {0.f, 0.f, 0.f, 0.f};                                     \
    floatx4 aZ = {0.f, 0.f, 0.f, 0.f};                                     \
    floatx4 aN = {0.f, 0.f, 0.f, 0.f};                                     \
    floatx4 aX = {0.f, 0.f, 0.f, 0.f};                                     \
    _Pragma("unroll") for (int kc = 0; kc < 16; ++kc) {                    \
      MFMA_BF16(aR, haf[kc], wR[kc]);                                      \
      MFMA_BF16(aZ, haf[kc], wZ[kc]);                                      \
      MFMA_BF16(aN, haf[kc], wHN[kc]);                                     \
    }                                                                      \
    MFMA_BF16(aR, xaf0, wR[16]);  MFMA_BF16(aR, xaf1, wR[17]);             \
    MFMA_BF16(aZ, xaf0, wZ[16]);  MFMA_BF16(aZ, xaf1, wZ[17]);             \
    MFMA_BF16(aX, xaf0, wXN[0]);  MFMA_BF16(aX, xaf1, wXN[1]);             \
    unsigned int* hd_ = hbuf + (size_t)(s & 1) * (B_ * H_);                \
    const unsigned int tg_ = ((unsigned int)(s + 1)) << 16;                \
    unsigned int hv_[4];                                                   \
    _Pragma("unroll") for (int i_ = 0; i_ < 4; ++i_) {                     \
      float rv = sigm(aR[i_] + brc);                                       \
      float zv = sigm(aZ[i_] + bzc);                                       \
      float nv = tanh_fast(aX[i_] + bxn + rv * (aN[i_] + bhn));            \
      float hn = (1.f - zv) * nv + zv * (HLOC)[i_];                        \
      (HLOC)[i_] = hn;                                                     \
      hv_[i_]    = tg_ | (unsigned int)f2bf(hn);                           \
    }                                                                      \
    _Pragma("unroll") for (int i_ = 0; i_ < 4; ++i_)                       \
        ast32(&hd_[(size_t)((RC) + quad * 4 + i_) * H_ + jg], hv_[i_]);    \
  } while (0)

// pass-boundary fc for one chain (reads its freshly staged LDS buffer)
#define FC_CHAIN(RC, hl)                                                   \
  do {                                                                     \
    const int mm  = lane & 15;                                             \
    const int sub = lane >> 4;                                             \
    _Pragma("unroll") for (int cc = 0; cc < 2; ++cc) {                     \
      const int c = ju * 2 + cc;                                           \
      const unsigned short* hrow = &hl[mm * LPAD + sub * 128];             \
      const float* wrow = fc_w + (size_t)c * H_ + sub * 128;               \
      float acc = 0.f;                                                     \
      _Pragma("unroll") for (int kk = 0; kk < 128; kk += 8) {              \
        short8 hv2 = *(const short8*)(hrow + kk);                          \
        _Pragma("unroll") for (int e = 0; e < 8; ++e)                      \
            acc = fmaf(bf2f((unsigned short)hv2[e]), wrow[kk + e], acc);   \
      }                                                                    \
      acc += __shfl_xor(acc, 16, 64);                                      \
      acc += __shfl_xor(acc, 32, 64);                                      \
      if (sub == 0) {                                                      \
        float val = acc + fc_b[c];                                         \
        out[((size_t)((RC) + mm) * HZ + p) * I_ + c] = val;                \
        ast32(&xext[((size_t)p * B_ + (RC) + mm) * I_ + c],                \
              (((unsigned int)(p + 1)) << 16) | (unsigned int)f2bf(val));  \
      }                                                                    \
    }                                                                      \
  } while (0)

extern "C" __global__ void __launch_bounds__(256, 1)
gru_chain(const float* __restrict__ x,       // [256][256][64] fp32
          const float* __restrict__ w_ih,    // [1536][64]   fp32
          const float* __restrict__ w_hh,    // [1536][512]  fp32
          const float* __restrict__ b_ih,    // [1536]       fp32
          const float* __restrict__ b_hh,    // [1536]       fp32
          const float* __restrict__ fc_w,    // [64][512]    fp32
          const float* __restrict__ fc_b,    // [64]         fp32
          float* __restrict__ out,           // [256][8][64] fp32
          unsigned int* __restrict__ hbuf,   // ws: [2][256][512] tagged u32
          unsigned int* __restrict__ xext)   // ws: [8][256][64]  tagged u32
{
  const int tid  = threadIdx.x;
  const int wave = tid >> 6;                  // 0..3
  const int lane = tid & 63;
  const int bx   = blockIdx.x;                // 0..63
  const int q    = bx & 7;                    // slab pair selector
  const int cblk = bx >> 3;                   // 0..7 column-block in group
  const int ju   = (cblk << 2) | wave;        // 0..31 j-tile unit in group
  const int n16  = lane & 15;
  const int quad = lane >> 4;
  const int jg   = ju * 16 + n16;             // output column j (0..511)
  const int rA   = q * 16;                    // chain A rows
  const int rB   = (q + 8) * 16;              // chain B rows

  __shared__ __align__(16) unsigned short hls[4 * HLSZ];  // 2 chains x 2 par
  unsigned short* hlsA = hls;
  unsigned short* hlsB = hls + 2 * HLSZ;

  // ---- one-time: fp32 weights -> bf16 B-fragments in registers ----
  // B-frag (16x16x32): lane holds B[k = kc*32 + quad*8 + e][n = lane&15];
  // B[k][j] = W[j][k] => weight row (gate*512+jg), cols kc*32+quad*8.
  short8 wR[18], wZ[18], wHN[16], wXN[2];
  {
    const int koff = quad * 8;
    const float* whr = w_hh + (size_t)(0 * H_ + jg) * H_ + koff;
    const float* whz = w_hh + (size_t)(1 * H_ + jg) * H_ + koff;
    const float* whn = w_hh + (size_t)(2 * H_ + jg) * H_ + koff;
#pragma unroll
    for (int kc = 0; kc < 16; ++kc) {
      wR[kc]  = ld8_f32_to_bf16(whr + kc * 32);
      wZ[kc]  = ld8_f32_to_bf16(whz + kc * 32);
      wHN[kc] = ld8_f32_to_bf16(whn + kc * 32);
    }
    const float* wir = w_ih + (size_t)(0 * H_ + jg) * I_ + koff;
    const float* wiz = w_ih + (size_t)(1 * H_ + jg) * I_ + koff;
    const float* win = w_ih + (size_t)(2 * H_ + jg) * I_ + koff;
#pragma unroll
    for (int kc = 0; kc < 2; ++kc) {
      wR[16 + kc] = ld8_f32_to_bf16(wir + kc * 32);
      wZ[16 + kc] = ld8_f32_to_bf16(wiz + kc * 32);
      wXN[kc]     = ld8_f32_to_bf16(win + kc * 32);
    }
  }
  const float brc = b_ih[jg]          + b_hh[jg];
  const float bzc = b_ih[H_ + jg]     + b_hh[H_ + jg];
  const float bxn = b_ih[2 * H_ + jg];
  const float bhn = b_hh[2 * H_ + jg];

  float hlocA[4] = {0.f, 0.f, 0.f, 0.f};
  float hlocB[4] = {0.f, 0.f, 0.f, 0.f};
  unsigned long long vA[16], vB[16];   // in-flight sweeps (one per chain)

  int s = 0;
  for (int p = 0; p < HZ; ++p) {
    const int Tp = T_ + p;
    for (int t = 0; t < Tp; ++t) {
      // A-half (step s): TOP-issue vB for h^{s-1}_B (parity (s+1)&1, tag s;
      // B stored it at the end of the previous half-step). Verify vA
      // (issued one half-step ago, full flight).
      HALF_STEP(rA, hlsA, hlocA, vA, rB, vB, (s + 1) & 1, s >= 1);
      // B-half (step s): TOP-issue vA for h^s_A (parity s&1, tag s+1;
      // A stored it just above). Verify vB (in flight across A's half).
      HALF_STEP(rB, hlsB, hlocB, vB, rA, vA, s & 1, 1);
      ++s;
    }
    // ---- pass boundary: pred_p = h_final @ fc_w^T + fc_b (both chains) ----
    {
      // vA is in flight (issued in the last B-half, parity (s+1)&1, tag s).
      // Issue vB now; fc-A below covers its flight time.
      ISSUE_SWEEP(vB, rB, (s + 1) & 1);
      unsigned short* hlA = hlsA + (s & 1) * HLSZ;
      VERIFY_STAGE(vA, rA, (s + 1) & 1, s, hlA);
      __syncthreads();
      FC_CHAIN(rA, hlA);
      unsigned short* hlB = hlsB + (s & 1) * HLSZ;
      VERIFY_STAGE(vB, rB, (s + 1) & 1, s, hlB);
      __syncthreads();
      FC_CHAIN(rB, hlB);
      __syncthreads();   // fc reads done before next pass restages LDS
      // prime vA for the next pass's first A-half (it verifies h^{s-1},
      // parity (s+1)&1 — the data just consumed, already tagged s).
      if (p + 1 < HZ) ISSUE_SWEEP(vA, rA, (s + 1) & 1);
    }
  }
}

extern "C" void kernel_launch(void* const* d_in, const int* in_sizes, int n_in,
                              void* d_out, int out_size, void* d_ws, size_t ws_size,
                              hipStream_t stream) {
  const float* x    = (const float*)d_in[0];
  const float* w_ih = (const float*)d_in[1];
  const float* w_hh = (const float*)d_in[2];
  const float* b_ih = (const float*)d_in[3];
  const float* b_hh = (const float*)d_in[4];
  const float* fc_w = (const float*)d_in[5];
  const float* fc_b = (const float*)d_in[6];
  float* out = (float*)d_out;

  unsigned char* ws = (unsigned char*)d_ws;
  const size_t hbuf_b = (size_t)2 * B_ * H_ * 4;   // 1 MiB (tagged u32)
  const size_t xext_b = (size_t)HZ * B_ * I_ * 4;  // 512 KiB (tagged u32)
  unsigned int* hbuf = (unsigned int*)ws;
  unsigned int* xext = (unsigned int*)(ws + hbuf_b);

  // zero tags (0 = invalid; the harness's 0xAA poison is also invalid)
  hipMemsetAsync(d_ws, 0, hbuf_b + xext_b, stream);

  // 64 blocks, 2 independent chains per block — all co-resident
  gru_chain<<<dim3(64), dim3(256), 0, stream>>>(
      x, w_ih, w_hh, b_ih, b_hh, fc_w, fc_b, out, hbuf, xext);
}

// Round 8
// 6179.990 us; speedup vs baseline: 2.6432x; 2.6432x over previous
//
#include <hip/hip_runtime.h>

// PredictorRNN: 2076 sequential GRU steps in ONE persistent kernel.
// Round-18 = round-15 champion (6173us) with the AIMD pre-delay RETUNED.
// r16/r17 falsified intra-block two-chain overlap from both directions
// (issue-late: zero overlap, 12.2ms; issue-early: stale sample + barrier
// vmcnt drain, 16.3ms + FETCH +23%). The 16 row-groups already run as
// independent chains across blocks; the per-chain step floor is
// store-visibility (~2600cy) + sweep RTT. r15's AIMD cap (12 quanta =
// ~1536cy, +2/-1 => ~33% first-sweep failure, FETCH unchanged) was under-
// tuned vs the calibrated ~2600cy visibility. Retune: +4 on fail, -1 on
// success, cap 24 (~3072cy) => equilibrium ~20% failure with the delay
// settled at true visibility; retry RTTs become cheap sleep that overlaps
// the x-prefetch. Everything else byte-identical to r15:
// tagged u32 (step_tag<<16|bf16) via relaxed agent-scope atomics
// (MALL-coherent); consumers poll the data itself (detection == arrival);
// distance-2 overwrite safety by parity; compute-then-4-stores epilogue.
// 128 blocks x 256 threads (4 waves => 512-VGPR budget; weights stay
// register-resident — 512-thread blocks cap at 256 VGPR and SPILL: round-9).

typedef __attribute__((ext_vector_type(8))) short short8;   // 8 x bf16 frag
typedef __attribute__((ext_vector_type(4))) float floatx4;

#define B_    256
#define T_    256
#define I_    64
#define H_    512
#define HZ    8
#define LPAD  520            // LDS staging pitch (ushorts), rows 16B-aligned
#define HLSZ  (16 * LPAD)    // one staging buffer (16 rows)

#define MFMA_BF16(acc, a, b) \
  acc = __builtin_amdgcn_mfma_f32_16x16x32_bf16((a), (b), (acc), 0, 0, 0)

// escalating backoff for the (rare, 28-step) tagged xext poll — champion tuning
#define POLL_BACKOFF(it)                         \
  do {                                           \
    if ((it) < 2)      __builtin_amdgcn_s_sleep(1);  \
    else if ((it) < 8) __builtin_amdgcn_s_sleep(4);  \
    else               __builtin_amdgcn_s_sleep(16); \
  } while (0)

__device__ __forceinline__ float bf2f(unsigned short u) {
  union { unsigned int i; float f; } v; v.i = ((unsigned int)u) << 16; return v.f;
}
__device__ __forceinline__ unsigned short f2bf(float f) {
  union { float f; unsigned int i; } v; v.f = f;
  return (unsigned short)((v.i + 0x7FFFu + ((v.i >> 16) & 1u)) >> 16);  // RNE
}
__device__ __forceinline__ short8 ld8_f32_to_bf16(const float* p) {
  short8 r;
#pragma unroll
  for (int e = 0; e < 8; ++e) r[e] = (short)f2bf(p[e]);
  return r;
}
__device__ __forceinline__ float sigm(float xx) {
  return __builtin_amdgcn_rcpf(1.f + __expf(-xx));
}
__device__ __forceinline__ float tanh_fast(float xx) {
  float e = __expf(2.f * xx);                 // +inf -> 1, 0 -> -1
  return 1.f - 2.f * __builtin_amdgcn_rcpf(e + 1.f);
}
// relaxed agent-scope atomics (lower to global ops with L1/L2 bypass -> MALL)
__device__ __forceinline__ unsigned long long ald64(const unsigned int* p) {
  return __hip_atomic_load((const unsigned long long*)p, __ATOMIC_RELAXED,
                           __HIP_MEMORY_SCOPE_AGENT);
}
__device__ __forceinline__ void ast32(unsigned int* p, unsigned int v) {
  __hip_atomic_store(p, v, __ATOMIC_RELAXED, __HIP_MEMORY_SCOPE_AGENT);
}

// ---- tagged h staging with ADAPTIVE PRE-DELAY (retuned AIMD) ----
// thread's slice: row i (i=0..15), 8B at word offset 2*tid within the row.
// Sleep dly quanta (~128cy each) so peer stores are visible when the first
// sweep samples the MALL; AIMD: fail => dly+4, clean => dly-1, cap 24
// (~3072cy) — settles at the ~2600cy visibility latency, ~20% equilibrium
// failure. Retries (rare once tuned) reload only stale words, flat sleep(2).
__device__ __forceinline__ void stage_h16(unsigned short* hl,
                                          const unsigned int* hb,
                                          unsigned int want, int tid,
                                          int& dly) {
  for (int i = 0; i < dly; ++i) __builtin_amdgcn_s_sleep(2);
  unsigned long long v[16];
#pragma unroll
  for (int i = 0; i < 16; ++i)
    v[i] = ald64(hb + (size_t)i * H_ + 2 * tid);
  bool fail1 = false;
  int it = 0;
  for (;;) {
    bool all = true;
#pragma unroll
    for (int i = 0; i < 16; ++i) {
      unsigned int w0 = (unsigned int)v[i];
      unsigned int w1 = (unsigned int)(v[i] >> 32);
      if (((w0 >> 16) != want) || ((w1 >> 16) != want)) all = false;
    }
    if (all) break;
    if (it == 0) fail1 = true;
    __builtin_amdgcn_s_sleep(2);
#pragma unroll
    for (int i = 0; i < 16; ++i) {
      unsigned int w0 = (unsigned int)v[i];
      unsigned int w1 = (unsigned int)(v[i] >> 32);
      if (((w0 >> 16) != want) || ((w1 >> 16) != want))
        v[i] = ald64(hb + (size_t)i * H_ + 2 * tid);
    }
    ++it;
  }
  // AIMD update (wave-uniform): converge to the visibility latency
  if (__any((int)fail1)) { if (dly < 24) dly += 4; }
  else                   { if (dly > 0)  dly -= 1; }
#pragma unroll
  for (int i = 0; i < 16; ++i) {
    unsigned int w0 = (unsigned int)v[i];
    unsigned int w1 = (unsigned int)(v[i] >> 32);
    *(unsigned int*)&hl[i * LPAD + 2 * tid] = (w0 & 0xffffu) | (w1 << 16);
  }
}

extern "C" __global__ void __launch_bounds__(256, 1)
gru_chain(const float* __restrict__ x,       // [256][256][64] fp32
          const float* __restrict__ w_ih,    // [1536][64]   fp32
          const float* __restrict__ w_hh,    // [1536][512]  fp32
          const float* __restrict__ b_ih,    // [1536]       fp32
          const float* __restrict__ b_hh,    // [1536]       fp32
          const float* __restrict__ fc_w,    // [64][512]    fp32
          const float* __restrict__ fc_b,    // [64]         fp32
          float* __restrict__ out,           // [256][8][64] fp32
          unsigned int* __restrict__ hbuf,   // ws: [2][256][512] tagged u32
          unsigned int* __restrict__ xext)   // ws: [8][256][64]  tagged u32
{
  const int tid  = threadIdx.x;
  const int wave = tid >> 6;                  // 0..3
  const int lane = tid & 63;
  const int bx   = blockIdx.x;                // 0..127
  const int grp  = bx & 15;                   // 16 groups x 8 blocks
  const int ju   = ((bx >> 4) << 2) | wave;   // 0..31 j-tile unit in group
  const int n16  = lane & 15;
  const int quad = lane >> 4;
  const int jg   = ju * 16 + n16;             // output column j (0..511)
  const int rowbase = grp * 16;               // 16 batch rows per group

  __shared__ __align__(16) unsigned short hls[2 * HLSZ];  // double-buffered

  // ---- one-time: fp32 weights -> bf16 B-fragments in registers ----
  // B-frag (16x16x32): lane holds B[k = kc*32 + quad*8 + e][n = lane&15];
  // B[k][j] = W[j][k] => weight row (gate*512+jg), cols kc*32+quad*8.
  short8 wR[18], wZ[18], wHN[16], wXN[2];
  {
    const int koff = quad * 8;
    const float* whr = w_hh + (size_t)(0 * H_ + jg) * H_ + koff;
    const float* whz = w_hh + (size_t)(1 * H_ + jg) * H_ + koff;
    const float* whn = w_hh + (size_t)(2 * H_ + jg) * H_ + koff;
#pragma unroll
    for (int kc = 0; kc < 16; ++kc) {
      wR[kc]  = ld8_f32_to_bf16(whr + kc * 32);
      wZ[kc]  = ld8_f32_to_bf16(whz + kc * 32);
      wHN[kc] = ld8_f32_to_bf16(whn + kc * 32);
    }
    const float* wir = w_ih + (size_t)(0 * H_ + jg) * I_ + koff;
    const float* wiz = w_ih + (size_t)(1 * H_ + jg) * I_ + koff;
    const float* win = w_ih + (size_t)(2 * H_ + jg) * I_ + koff;
#pragma unroll
    for (int kc = 0; kc < 2; ++kc) {
      wR[16 + kc] = ld8_f32_to_bf16(wir + kc * 32);
      wZ[16 + kc] = ld8_f32_to_bf16(wiz + kc * 32);
      wXN[kc]     = ld8_f32_to_bf16(win + kc * 32);
    }
  }
  const float brc = b_ih[jg]          + b_hh[jg];
  const float bzc = b_ih[H_ + jg]     + b_hh[H_ + jg];
  const float bxn = b_ih[2 * H_ + jg];
  const float bhn = b_hh[2 * H_ + jg];

  float hloc[4] = {0.f, 0.f, 0.f, 0.f};   // fp32 recurrent carry (C/D layout)
  int   dly = 8;                           // adaptive pre-delay (sleep quanta)

  int s = 0;
  for (int p = 0; p < HZ; ++p) {
    const int Tp = T_ + p;
    for (int t = 0; t < Tp; ++t) {
      // ---- x A-fragment (prefetch overlaps the h pre-delay + sweep) ----
      short8 xaf0, xaf1;
      if (t < T_) {
        const float* xs = x + ((size_t)(rowbase + n16) * T_ + t) * I_ + quad * 8;
        xaf0 = ld8_f32_to_bf16(xs);
        xaf1 = ld8_f32_to_bf16(xs + 32);
      }
      // ---- stage h^(s-1) (tagged, self-synchronizing) into LDS[s&1] ----
      unsigned short* hl = &hls[(s & 1) * HLSZ];
      if (s > 0) {
        const unsigned int* hb = hbuf + (size_t)((s + 1) & 1) * (B_ * H_) +
                                 (size_t)rowbase * H_;
        stage_h16(hl, hb, (unsigned int)s, tid, dly);
      } else {  // s == 0: h_prev = 0
#pragma unroll
        for (int i = 0; i < 16; ++i)
          *(unsigned int*)&hl[i * LPAD + 2 * tid] = 0u;
      }
      // ---- xext A-fragment for appended timesteps (tagged, rare) ----
      if (t >= T_) {
        const int p2 = t - T_;
        const unsigned int wantx = (unsigned int)(p2 + 1);
        const unsigned int* xb =
            xext + ((size_t)p2 * B_ + rowbase + n16) * I_;
        unsigned long long u[8];
#pragma unroll
        for (int k = 0; k < 8; ++k) {
          int off = (k < 4) ? (quad * 8 + 2 * k) : (32 + quad * 8 + 2 * (k - 4));
          u[k] = ald64(xb + off);
        }
        int it = 0;
        for (;;) {
          bool all = true;
#pragma unroll
          for (int k = 0; k < 8; ++k) {
            unsigned int w0 = (unsigned int)u[k];
            unsigned int w1 = (unsigned int)(u[k] >> 32);
            if (((w0 >> 16) != wantx) || ((w1 >> 16) != wantx)) {
              all = false;
              int off = (k < 4) ? (quad * 8 + 2 * k)
                                : (32 + quad * 8 + 2 * (k - 4));
              u[k] = ald64(xb + off);
            }
          }
          if (all) break;
          POLL_BACKOFF(it);
          ++it;
        }
#pragma unroll
        for (int k = 0; k < 4; ++k) {
          xaf0[2 * k]     = (short)(unsigned short)u[k];
          xaf0[2 * k + 1] = (short)(unsigned short)(u[k] >> 32);
          xaf1[2 * k]     = (short)(unsigned short)u[4 + k];
          xaf1[2 * k + 1] = (short)(unsigned short)(u[4 + k] >> 32);
        }
      }
      __syncthreads();   // staging visible; also protects LDS parity reuse
      short8 haf[16];
#pragma unroll
      for (int kc = 0; kc < 16; ++kc)
        haf[kc] = *(const short8*)&hl[n16 * LPAD + kc * 32 + quad * 8];

      floatx4 aR = {0.f, 0.f, 0.f, 0.f};
      floatx4 aZ = {0.f, 0.f, 0.f, 0.f};
      floatx4 aN = {0.f, 0.f, 0.f, 0.f};
      floatx4 aX = {0.f, 0.f, 0.f, 0.f};
#pragma unroll
      for (int kc = 0; kc < 16; ++kc) {
        MFMA_BF16(aR, haf[kc], wR[kc]);
        MFMA_BF16(aZ, haf[kc], wZ[kc]);
        MFMA_BF16(aN, haf[kc], wHN[kc]);
      }
      MFMA_BF16(aR, xaf0, wR[16]);  MFMA_BF16(aR, xaf1, wR[17]);
      MFMA_BF16(aZ, xaf0, wZ[16]);  MFMA_BF16(aZ, xaf1, wZ[17]);
      MFMA_BF16(aX, xaf0, wXN[0]);  MFMA_BF16(aX, xaf1, wXN[1]);

      // ---- epilogue: compute all 4 h values, then stores back-to-back ----
      // (earlier last-store issue => earlier MALL visibility for peers)
      unsigned int* hd = hbuf + (size_t)(s & 1) * (B_ * H_);
      const unsigned int tg = ((unsigned int)(s + 1)) << 16;
      unsigned int hv[4];
#pragma unroll
      for (int i = 0; i < 4; ++i) {
        float rv = sigm(aR[i] + brc);
        float zv = sigm(aZ[i] + bzc);
        float nv = tanh_fast(aX[i] + bxn + rv * (aN[i] + bhn));
        float hn = (1.f - zv) * nv + zv * hloc[i];
        hloc[i]  = hn;
        hv[i]    = tg | (unsigned int)f2bf(hn);
      }
#pragma unroll
      for (int i = 0; i < 4; ++i)
        ast32(&hd[(size_t)(rowbase + quad * 4 + i) * H_ + jg], hv[i]);
      ++s;
    }
    // ---- pass boundary: pred_p = h_final @ fc_w^T + fc_b ----
    {
      unsigned short* hl = &hls[(s & 1) * HLSZ];
      const unsigned int* hb = hbuf + (size_t)((s + 1) & 1) * (B_ * H_) +
                               (size_t)rowbase * H_;
      stage_h16(hl, hb, (unsigned int)s, tid, dly);
      __syncthreads();
      const int mm  = lane & 15;
      const int sub = lane >> 4;
#pragma unroll
      for (int cc = 0; cc < 2; ++cc) {
        const int c = ju * 2 + cc;
        const unsigned short* hrow = &hl[mm * LPAD + sub * 128];
        const float* wrow = fc_w + (size_t)c * H_ + sub * 128;
        float acc = 0.f;
#pragma unroll
        for (int kk = 0; kk < 128; kk += 8) {
          short8 hv2 = *(const short8*)(hrow + kk);
#pragma unroll
          for (int e = 0; e < 8; ++e)
            acc = fmaf(bf2f((unsigned short)hv2[e]), wrow[kk + e], acc);
        }
        acc += __shfl_xor(acc, 16, 64);
        acc += __shfl_xor(acc, 32, 64);
        if (sub == 0) {
          float val = acc + fc_b[c];
          out[((size_t)(rowbase + mm) * HZ + p) * I_ + c] = val;   // fp32
          ast32(&xext[((size_t)p * B_ + rowbase + mm) * I_ + c],
                (((unsigned int)(p + 1)) << 16) | (unsigned int)f2bf(val));
        }
      }
      __syncthreads();   // fc reads done before next pass restages LDS[s&1]
    }
  }
}

extern "C" void kernel_launch(void* const* d_in, const int* in_sizes, int n_in,
                              void* d_out, int out_size, void* d_ws, size_t ws_size,
                              hipStream_t stream) {
  const float* x    = (const float*)d_in[0];
  const float* w_ih = (const float*)d_in[1];
  const float* w_hh = (const float*)d_in[2];
  const float* b_ih = (const float*)d_in[3];
  const float* b_hh = (const float*)d_in[4];
  const float* fc_w = (const float*)d_in[5];
  const float* fc_b = (const float*)d_in[6];
  float* out = (float*)d_out;

  unsigned char* ws = (unsigned char*)d_ws;
  const size_t hbuf_b = (size_t)2 * B_ * H_ * 4;   // 1 MiB (tagged u32)
  const size_t xext_b = (size_t)HZ * B_ * I_ * 4;  // 512 KiB (tagged u32)
  unsigned int* hbuf = (unsigned int*)ws;
  unsigned int* xext = (unsigned int*)(ws + hbuf_b);

  // zero tags (0 = invalid; the harness's 0xAA poison is also invalid)
  hipMemsetAsync(d_ws, 0, hbuf_b + xext_b, stream);

  // 128 blocks on 256 CUs — all co-resident (self-sync safe)
  gru_chain<<<dim3(128), dim3(256), 0, stream>>>(
      x, w_ih, w_hh, b_ih, b_hh, fc_w, fc_b, out, hbuf, xext);
}